// Round 1
// baseline (105.664 us; speedup 1.0000x reference)
//
#include <hip/hip_runtime.h>
#include <math.h>

// One wave (64 lanes) per sample. Block = 256 threads = 4 waves = 4 samples.
// Encoder + normalize + Gabriel in fp64 (adjacency bits must match the fp64
// numpy reference exactly); GAT1/GAT2/decoder in fp32 (continuous outputs,
// threshold ~0.14).

struct alignas(16) WaveScratch {
  union Big {
    double d[8][68];      // encoder h1 / h2 (doubles)
    float  f[2][8][68];   // fA, fB (floats), same storage
  } big;
  float  alphaS[64];
  float  latSf[24];
  float  xl2S[24];
  float  xr2S[24];
  float  combS[24];
  double latSd[24];
  double visSd[24];
};

__global__ __launch_bounds__(256)
void gae_fused(const float* __restrict__ x,
               const float* __restrict__ enc_w1, const float* __restrict__ enc_b1,
               const float* __restrict__ enc_w2, const float* __restrict__ enc_b2,
               const float* __restrict__ enc_w3, const float* __restrict__ enc_b3,
               const float* __restrict__ g1_wl, const float* __restrict__ g1_bl,
               const float* __restrict__ g1_wr, const float* __restrict__ g1_br,
               const float* __restrict__ g1_we, const float* __restrict__ g1_att,
               const float* __restrict__ g1_bias,
               const float* __restrict__ g2_wl, const float* __restrict__ g2_bl,
               const float* __restrict__ g2_wr, const float* __restrict__ g2_br,
               const float* __restrict__ g2_we, const float* __restrict__ g2_att,
               const float* __restrict__ g2_bias,
               const float* __restrict__ skip_w, const float* __restrict__ skip_b,
               const float* __restrict__ dec_w1, const float* __restrict__ dec_b1,
               const float* __restrict__ dec_w2, const float* __restrict__ dec_b2,
               const float* __restrict__ dec_w3, const float* __restrict__ dec_b3,
               float* __restrict__ out, int B)
{
  __shared__ WaveScratch ws4[4];
  __shared__ __align__(16) float s_w3e[192];
  __shared__ __align__(16) float s_w3d[192];
  __shared__ __align__(16) float s_g2wl[192];
  __shared__ __align__(16) float s_g2wr[192];
  __shared__ __align__(16) float s_we1[64];
  __shared__ __align__(16) float s_att1[64];
  __shared__ float s_skw[9], s_skb[3], s_b3e[3], s_b3d[3];
  __shared__ float s_g2bl[3], s_g2br[3], s_g2we[3], s_g2att[3], s_g2bias[3];

  const int tid  = threadIdx.x;
  const int wid  = tid >> 6;
  const int lane = tid & 63;

  // ---- stage small weights into LDS (cooperative) ----
  if (tid < 192) { s_w3e[tid] = enc_w3[tid]; s_w3d[tid] = dec_w3[tid];
                   s_g2wl[tid] = g2_wl[tid]; s_g2wr[tid] = g2_wr[tid]; }
  if (tid < 64)  { s_we1[tid] = g1_we[tid];  s_att1[tid] = g1_att[tid]; }
  if (tid < 9)   s_skw[tid] = skip_w[tid];
  if (tid < 3)   { s_skb[tid] = skip_b[tid]; s_b3e[tid] = enc_b3[tid]; s_b3d[tid] = dec_b3[tid];
                   s_g2bl[tid] = g2_bl[tid]; s_g2br[tid] = g2_br[tid]; s_g2we[tid] = g2_we[tid];
                   s_g2att[tid] = g2_att[tid]; s_g2bias[tid] = g2_bias[tid]; }

  const int s = blockIdx.x * 4 + wid;
  const bool active = (s < B);
  const int sc = active ? s : 0;            // clamped sample for safe reads
  WaveScratch& W = ws4[wid];

  // per-lane register weights (lane = hidden channel c)
  const double ew1n = (double)enc_w1[64 + lane];
  const double ew1x = (double)enc_w1[128 + lane];
  const double eb1d = (double)enc_b1[lane];
  const double eb2d = (double)enc_b2[lane];
  const float wl0 = g1_wl[lane], wl1 = g1_wl[64 + lane], wl2 = g1_wl[128 + lane], blc = g1_bl[lane];
  const float wr0 = g1_wr[lane], wr1 = g1_wr[64 + lane], wr2 = g1_wr[128 + lane], brc = g1_br[lane];
  const float g1bias_c = g1_bias[lane];
  const float dwc0 = dec_w1[lane], dwc1 = dec_w1[64 + lane], dwc2 = dec_w1[128 + lane];
  const float db1c = dec_b1[lane], db2c = dec_b2[lane];

  __syncthreads();   // weights staged

  // ---- xp output + encoder layer 1 (fp64) ----
  const float* xb = x + (size_t)sc * 8;
  if (active && lane < 24) {
    const int r = lane, n = r / 3, l = r - n * 3;
    float v = (l == 0) ? 0.0f : ((l == 1) ? (float)n : xb[n]);
    out[(size_t)s * 24 + r] = v;
  }
  #pragma unroll
  for (int n = 0; n < 8; ++n) {
    double v = (double)n * ew1n + (double)xb[n] * ew1x + eb1d;
    W.big.d[n][lane] = v > 0.0 ? v : 0.0;
  }
  __syncthreads();

  // ---- encoder layer 2 (fp64): h2[n][c] = relu(sum_k h1[n][k]*w2[k][c]+b2) ----
  double acc2[8];
  #pragma unroll
  for (int n = 0; n < 8; ++n) acc2[n] = eb2d;
  #pragma unroll
  for (int ch = 0; ch < 4; ++ch) {
    double wcd[16];
    #pragma unroll
    for (int t = 0; t < 16; ++t) wcd[t] = (double)enc_w2[(ch * 16 + t) * 64 + lane];
    #pragma unroll
    for (int t2 = 0; t2 < 8; ++t2) {
      #pragma unroll
      for (int n = 0; n < 8; ++n) {
        const double2 hv = *(const double2*)&W.big.d[n][ch * 16 + t2 * 2];
        acc2[n] = fma(hv.x, wcd[t2 * 2], acc2[n]);
        acc2[n] = fma(hv.y, wcd[t2 * 2 + 1], acc2[n]);
      }
    }
  }
  __syncthreads();     // all h1 reads complete
  #pragma unroll
  for (int n = 0; n < 8; ++n) W.big.d[n][lane] = acc2[n] > 0.0 ? acc2[n] : 0.0;
  __syncthreads();

  // ---- latent projection (fp64, lanes<24) ----
  if (lane < 24) {
    const int r = lane, n = r / 3, l = r - n * 3;
    double a = (double)s_b3e[l];
    #pragma unroll 8
    for (int k = 0; k < 64; ++k) a = fma(W.big.d[n][k], (double)s_w3e[k * 3 + l], a);
    W.latSd[r] = a;
    W.latSf[r] = (float)a;
  }
  __syncthreads();

  // ---- normalize -> vis (fp64, lanes<24) ----
  if (lane < 24) {
    const int r = lane, n = r / 3, l = r - n * 3; (void)n;
    double s1 = 0.0;
    #pragma unroll
    for (int q = 0; q < 8; ++q) s1 += W.latSd[q * 3 + l];
    const double m = s1 * 0.125;
    double s2 = 0.0;
    #pragma unroll
    for (int q = 0; q < 8; ++q) s2 += (W.latSd[q * 3 + l] - m);
    const double m2 = s2 * 0.125;
    double s3 = 0.0;
    #pragma unroll
    for (int q = 0; q < 8; ++q) { double dv = W.latSd[q * 3 + l] - m - m2; s3 += dv * dv; }
    const double stdv = sqrt(s3 / 7.0) + 1e-8;
    const double visv = (W.latSd[r] - m) / stdv;
    W.visSd[r] = visv;
    if (active) out[(size_t)B * 48 + (size_t)s * 24 + r] = (float)visv;
  }
  __syncthreads();

  // ---- Gabriel graph (fp64, lane = (i,j)) ----
  const int gi = lane >> 3, gj = lane & 7;
  const double pi0 = W.visSd[gi * 3], pi1 = W.visSd[gi * 3 + 1], pi2 = W.visSd[gi * 3 + 2];
  const double pj0 = W.visSd[gj * 3], pj1 = W.visSd[gj * 3 + 1], pj2 = W.visSd[gj * 3 + 2];
  const double mid0 = (pi0 + pj0) * 0.5, mid1 = (pi1 + pj1) * 0.5, mid2 = (pi2 + pj2) * 0.5;
  const double dr0 = pi0 - mid0, dr1 = pi1 - mid1, dr2 = pi2 - mid2;
  const double r2 = dr0 * dr0 + dr1 * dr1 + dr2 * dr2;
  bool viol = false;
  #pragma unroll
  for (int k = 0; k < 8; ++k) {
    const double a0 = W.visSd[k * 3] - mid0;
    const double a1 = W.visSd[k * 3 + 1] - mid1;
    const double a2 = W.visSd[k * 3 + 2] - mid2;
    const double d2 = a0 * a0 + a1 * a1 + a2 * a2;
    viol = viol || ((k != gi) && (k != gj) && (d2 < r2));
  }
  const double dd0 = pi0 - pj0, dd1 = pi1 - pj1, dd2 = pi2 - pj2;
  const double distd = sqrt(dd0 * dd0 + dd1 * dd1 + dd2 * dd2 + 1e-30);
  const bool adjb  = (!viol) && (gi != gj);
  const bool maskb = adjb || (gi == gj);
  const float adjf = adjb ? 1.0f : 0.0f;
  if (active) out[(size_t)B * 72 + (size_t)s * 64 + lane] = adjf;
  const float distf = (float)distd;
  float ne = adjf, sd = adjb ? distf : 0.0f;
  #pragma unroll
  for (int d = 1; d < 64; d <<= 1) { ne += __shfl_xor(ne, d); sd += __shfl_xor(sd, d); }
  const float mean_attr = sd / fmaxf(ne, 1.0f);
  const float eat = (gi == gj) ? mean_attr : distf;

  // ---- GAT1 source/target transforms (fp32, lane = channel) ----
  float xlr[8], xrr[8];
  #pragma unroll
  for (int n = 0; n < 8; ++n) {
    const float a0 = W.latSf[n * 3], a1 = W.latSf[n * 3 + 1], a2 = W.latSf[n * 3 + 2];
    xlr[n] = fmaf(a2, wl2, fmaf(a1, wl1, fmaf(a0, wl0, blc)));
    xrr[n] = fmaf(a2, wr2, fmaf(a1, wr1, fmaf(a0, wr0, brc)));
    W.big.f[0][n][lane] = xlr[n];
    W.big.f[1][n][lane] = xrr[n];
  }
  __syncthreads();

  // ---- GAT1 attention logits (lane = (i,j)) ----
  float ev = 0.0f;
  #pragma unroll
  for (int c4 = 0; c4 < 16; ++c4) {
    const float4 xlv = *(const float4*)&W.big.f[0][gj][c4 * 4];
    const float4 xrv = *(const float4*)&W.big.f[1][gi][c4 * 4];
    const float4 wev = *(const float4*)&s_we1[c4 * 4];
    const float4 atv = *(const float4*)&s_att1[c4 * 4];
    float h;
    h = fmaf(eat, wev.x, xrv.x + xlv.x); ev = fmaf(fmaxf(h, 0.f) + 0.2f * fminf(h, 0.f), atv.x, ev);
    h = fmaf(eat, wev.y, xrv.y + xlv.y); ev = fmaf(fmaxf(h, 0.f) + 0.2f * fminf(h, 0.f), atv.y, ev);
    h = fmaf(eat, wev.z, xrv.z + xlv.z); ev = fmaf(fmaxf(h, 0.f) + 0.2f * fminf(h, 0.f), atv.z, ev);
    h = fmaf(eat, wev.w, xrv.w + xlv.w); ev = fmaf(fmaxf(h, 0.f) + 0.2f * fminf(h, 0.f), atv.w, ev);
  }
  {
    float em = maskb ? ev : -1e30f;
    float mx = em;
    mx = fmaxf(mx, __shfl_xor(mx, 1)); mx = fmaxf(mx, __shfl_xor(mx, 2)); mx = fmaxf(mx, __shfl_xor(mx, 4));
    float p = __expf(em - mx);
    float ssum = p;
    ssum += __shfl_xor(ssum, 1); ssum += __shfl_xor(ssum, 2); ssum += __shfl_xor(ssum, 4);
    W.alphaS[lane] = (p / ssum) * (maskb ? 1.0f : 0.0f);
  }
  __syncthreads();

  // ---- GAT1 aggregation + relu (lane = channel) ----
  float hg[8];
  #pragma unroll
  for (int i = 0; i < 8; ++i) {
    const float4 q0 = *(const float4*)&W.alphaS[i * 8];
    const float4 q1 = *(const float4*)&W.alphaS[i * 8 + 4];
    float a = g1bias_c;
    a = fmaf(q0.x, xlr[0], a); a = fmaf(q0.y, xlr[1], a);
    a = fmaf(q0.z, xlr[2], a); a = fmaf(q0.w, xlr[3], a);
    a = fmaf(q1.x, xlr[4], a); a = fmaf(q1.y, xlr[5], a);
    a = fmaf(q1.z, xlr[6], a); a = fmaf(q1.w, xlr[7], a);
    hg[i] = fmaxf(a, 0.0f);
  }
  __syncthreads();            // everyone done reading fA/fB + alphaS
  #pragma unroll
  for (int i = 0; i < 8; ++i) W.big.f[0][i][lane] = hg[i];
  __syncthreads();

  // ---- GAT2 transforms (lanes<48: 24 for xl2, 24 for xr2) ----
  if (lane < 48) {
    const int g = lane / 24, r = lane - g * 24, n = r / 3, l = r - n * 3;
    const float* wsel = g ? s_g2wr : s_g2wl;
    float a = g ? s_g2br[l] : s_g2bl[l];
    #pragma unroll 8
    for (int k = 0; k < 64; ++k) a = fmaf(W.big.f[0][n][k], wsel[k * 3 + l], a);
    if (g) W.xr2S[r] = a; else W.xl2S[r] = a;
  }
  __syncthreads();

  // ---- GAT2 attention (lane = (i,j)) ----
  float e2 = 0.0f;
  #pragma unroll
  for (int l = 0; l < 3; ++l) {
    const float hh = fmaf(eat, s_g2we[l], W.xr2S[gi * 3 + l] + W.xl2S[gj * 3 + l]);
    e2 = fmaf(fmaxf(hh, 0.f) + 0.2f * fminf(hh, 0.f), s_g2att[l], e2);
  }
  {
    float em = maskb ? e2 : -1e30f;
    float mx = em;
    mx = fmaxf(mx, __shfl_xor(mx, 1)); mx = fmaxf(mx, __shfl_xor(mx, 2)); mx = fmaxf(mx, __shfl_xor(mx, 4));
    float p = __expf(em - mx);
    float ssum = p;
    ssum += __shfl_xor(ssum, 1); ssum += __shfl_xor(ssum, 2); ssum += __shfl_xor(ssum, 4);
    W.alphaS[lane] = (p / ssum) * (maskb ? 1.0f : 0.0f);
  }
  __syncthreads();

  // ---- GAT2 aggregation + skip connection (lanes<24) ----
  if (lane < 24) {
    const int r = lane, n = r / 3, l = r - n * 3;
    float a = s_g2bias[l];
    #pragma unroll
    for (int j = 0; j < 8; ++j) a = fmaf(W.alphaS[n * 8 + j], W.xl2S[j * 3 + l], a);
    const float cb = a + W.latSf[n * 3] * s_skw[l] + W.latSf[n * 3 + 1] * s_skw[3 + l]
                       + W.latSf[n * 3 + 2] * s_skw[6 + l] + s_skb[l];
    W.combS[r] = cb;
  }
  __syncthreads();

  // ---- decoder layer 1 (lane = channel) ----
  #pragma unroll
  for (int n = 0; n < 8; ++n) {
    const float c0 = W.combS[n * 3], c1 = W.combS[n * 3 + 1], c2 = W.combS[n * 3 + 2];
    const float d1 = fmaf(c2, dwc2, fmaf(c1, dwc1, fmaf(c0, dwc0, db1c)));
    W.big.f[0][n][lane] = fmaxf(d1, 0.0f);
  }
  __syncthreads();

  // ---- decoder layer 2 (fp32 64x64) ----
  float accf[8];
  #pragma unroll
  for (int n = 0; n < 8; ++n) accf[n] = db2c;
  #pragma unroll
  for (int ch = 0; ch < 2; ++ch) {
    float wc[32];
    #pragma unroll
    for (int t = 0; t < 32; ++t) wc[t] = dec_w2[(ch * 32 + t) * 64 + lane];
    #pragma unroll
    for (int t4 = 0; t4 < 8; ++t4) {
      #pragma unroll
      for (int n = 0; n < 8; ++n) {
        const float4 hv = *(const float4*)&W.big.f[0][n][ch * 32 + t4 * 4];
        accf[n] = fmaf(hv.x, wc[t4 * 4], accf[n]);
        accf[n] = fmaf(hv.y, wc[t4 * 4 + 1], accf[n]);
        accf[n] = fmaf(hv.z, wc[t4 * 4 + 2], accf[n]);
        accf[n] = fmaf(hv.w, wc[t4 * 4 + 3], accf[n]);
      }
    }
  }
  #pragma unroll
  for (int n = 0; n < 8; ++n) W.big.f[1][n][lane] = fmaxf(accf[n], 0.0f);
  __syncthreads();

  // ---- decoder output projection -> rec (lanes<24) ----
  if (active && lane < 24) {
    const int r = lane, n = r / 3, l = r - n * 3;
    float a = s_b3d[l];
    #pragma unroll 8
    for (int k = 0; k < 64; ++k) a = fmaf(W.big.f[1][n][k], s_w3d[k * 3 + l], a);
    out[(size_t)B * 24 + (size_t)s * 24 + r] = a;
  }
}

extern "C" void kernel_launch(void* const* d_in, const int* in_sizes, int n_in,
                              void* d_out, int out_size, void* d_ws, size_t ws_size,
                              hipStream_t stream) {
  const int B = in_sizes[0] / 8;
  const float* x       = (const float*)d_in[0];
  const float* enc_w1  = (const float*)d_in[1];
  const float* enc_b1  = (const float*)d_in[2];
  const float* enc_w2  = (const float*)d_in[3];
  const float* enc_b2  = (const float*)d_in[4];
  const float* enc_w3  = (const float*)d_in[5];
  const float* enc_b3  = (const float*)d_in[6];
  const float* g1_wl   = (const float*)d_in[7];
  const float* g1_bl   = (const float*)d_in[8];
  const float* g1_wr   = (const float*)d_in[9];
  const float* g1_br   = (const float*)d_in[10];
  const float* g1_we   = (const float*)d_in[11];
  const float* g1_att  = (const float*)d_in[12];
  const float* g1_bias = (const float*)d_in[13];
  const float* g2_wl   = (const float*)d_in[14];
  const float* g2_bl   = (const float*)d_in[15];
  const float* g2_wr   = (const float*)d_in[16];
  const float* g2_br   = (const float*)d_in[17];
  const float* g2_we   = (const float*)d_in[18];
  const float* g2_att  = (const float*)d_in[19];
  const float* g2_bias = (const float*)d_in[20];
  const float* skip_w  = (const float*)d_in[21];
  const float* skip_b  = (const float*)d_in[22];
  const float* dec_w1  = (const float*)d_in[23];
  const float* dec_b1  = (const float*)d_in[24];
  const float* dec_w2  = (const float*)d_in[25];
  const float* dec_b2  = (const float*)d_in[26];
  const float* dec_w3  = (const float*)d_in[27];
  const float* dec_b3  = (const float*)d_in[28];
  float* out = (float*)d_out;

  const int nblk = (B + 3) / 4;
  gae_fused<<<nblk, 256, 0, stream>>>(x,
      enc_w1, enc_b1, enc_w2, enc_b2, enc_w3, enc_b3,
      g1_wl, g1_bl, g1_wr, g1_br, g1_we, g1_att, g1_bias,
      g2_wl, g2_bl, g2_wr, g2_br, g2_we, g2_att, g2_bias,
      skip_w, skip_b, dec_w1, dec_b1, dec_w2, dec_b2, dec_w3, dec_b3,
      out, B);
}

// Round 2
// 95.405 us; speedup vs baseline: 1.1075x; 1.1075x over previous
//
#include <hip/hip_runtime.h>
#include <math.h>

// One wave (64 lanes) per sample. Block = 256 threads = 4 waves = 4 samples.
// All inter-phase synchronization is WAVE-LOCAL (scratch is per-wave), done
// with s_waitcnt lgkmcnt(0) fences instead of cross-wave __syncthreads.
// Encoder + normalize + Gabriel in fp64 (adjacency bits must match the fp64
// numpy reference); GAT1/GAT2/decoder in fp32 (continuous, threshold ~0.14).

#define WFENCE() asm volatile("s_waitcnt lgkmcnt(0)" ::: "memory")

struct alignas(16) WaveScratch {
  union Big {
    double d[8][68];      // encoder h1 / h2 (doubles)
    float  f[2][8][68];   // fA, fB (floats), same storage
  } big;
  float  alphaS[64];
  float  latSf[24];
  float  xl2S[24];
  float  xr2S[24];
  float  combS[24];
  double latSd[24];
  double visSd[24];
};

__global__ __launch_bounds__(256)
void gae_fused(const float* __restrict__ x,
               const float* __restrict__ enc_w1, const float* __restrict__ enc_b1,
               const float* __restrict__ enc_w2, const float* __restrict__ enc_b2,
               const float* __restrict__ enc_w3, const float* __restrict__ enc_b3,
               const float* __restrict__ g1_wl, const float* __restrict__ g1_bl,
               const float* __restrict__ g1_wr, const float* __restrict__ g1_br,
               const float* __restrict__ g1_we, const float* __restrict__ g1_att,
               const float* __restrict__ g1_bias,
               const float* __restrict__ g2_wl, const float* __restrict__ g2_bl,
               const float* __restrict__ g2_wr, const float* __restrict__ g2_br,
               const float* __restrict__ g2_we, const float* __restrict__ g2_att,
               const float* __restrict__ g2_bias,
               const float* __restrict__ skip_w, const float* __restrict__ skip_b,
               const float* __restrict__ dec_w1, const float* __restrict__ dec_b1,
               const float* __restrict__ dec_w2, const float* __restrict__ dec_b2,
               const float* __restrict__ dec_w3, const float* __restrict__ dec_b3,
               float* __restrict__ out, int B)
{
  __shared__ WaveScratch ws4[4];
  __shared__ __align__(16) float s_w3e[192];
  __shared__ __align__(16) float s_w3d[192];
  __shared__ __align__(16) float s_g2wl[192];
  __shared__ __align__(16) float s_g2wr[192];
  __shared__ __align__(16) float s_we1[64];
  __shared__ __align__(16) float s_att1[64];
  __shared__ float s_skw[9], s_skb[3], s_b3e[3], s_b3d[3];
  __shared__ float s_g2bl[3], s_g2br[3], s_g2we[3], s_g2att[3], s_g2bias[3];

  const int tid  = threadIdx.x;
  const int wid  = tid >> 6;
  const int lane = tid & 63;

  // ---- stage small weights into LDS (cooperative) ----
  if (tid < 192) { s_w3e[tid] = enc_w3[tid]; s_w3d[tid] = dec_w3[tid];
                   s_g2wl[tid] = g2_wl[tid]; s_g2wr[tid] = g2_wr[tid]; }
  if (tid < 64)  { s_we1[tid] = g1_we[tid];  s_att1[tid] = g1_att[tid]; }
  if (tid < 9)   s_skw[tid] = skip_w[tid];
  if (tid < 3)   { s_skb[tid] = skip_b[tid]; s_b3e[tid] = enc_b3[tid]; s_b3d[tid] = dec_b3[tid];
                   s_g2bl[tid] = g2_bl[tid]; s_g2br[tid] = g2_br[tid]; s_g2we[tid] = g2_we[tid];
                   s_g2att[tid] = g2_att[tid]; s_g2bias[tid] = g2_bias[tid]; }

  const int s = blockIdx.x * 4 + wid;
  const bool active = (s < B);
  const int sc = active ? s : 0;            // clamped sample for safe reads
  WaveScratch& W = ws4[wid];

  // per-lane register weights (lane = hidden channel c)
  const double ew1n = (double)enc_w1[64 + lane];
  const double ew1x = (double)enc_w1[128 + lane];
  const double eb1d = (double)enc_b1[lane];
  const double eb2d = (double)enc_b2[lane];
  const float wl0 = g1_wl[lane], wl1 = g1_wl[64 + lane], wl2 = g1_wl[128 + lane], blc = g1_bl[lane];
  const float wr0 = g1_wr[lane], wr1 = g1_wr[64 + lane], wr2 = g1_wr[128 + lane], brc = g1_br[lane];
  const float g1bias_c = g1_bias[lane];
  const float dwc0 = dec_w1[lane], dwc1 = dec_w1[64 + lane], dwc2 = dec_w1[128 + lane];
  const float db1c = dec_b1[lane], db2c = dec_b2[lane];

  __syncthreads();   // weights staged (the ONLY cross-wave barrier)

  // ---- xp output + encoder layer 1 (fp64) ----
  const float* xb = x + (size_t)sc * 8;
  if (active && lane < 24) {
    const int r = lane, n = r / 3, l = r - n * 3;
    float v = (l == 0) ? 0.0f : ((l == 1) ? (float)n : xb[n]);
    out[(size_t)s * 24 + r] = v;
  }
  #pragma unroll
  for (int n = 0; n < 8; ++n) {
    double v = (double)n * ew1n + (double)xb[n] * ew1x + eb1d;
    W.big.d[n][lane] = v > 0.0 ? v : 0.0;
  }
  WFENCE();                                  // h1 visible to wave

  // ---- encoder layer 2 (fp64): h2[n][c] = relu(sum_k h1[n][k]*w2[k][c]+b2) ----
  double acc2[8];
  #pragma unroll
  for (int n = 0; n < 8; ++n) acc2[n] = eb2d;
  #pragma unroll
  for (int ch = 0; ch < 4; ++ch) {
    double wcd[16];
    #pragma unroll
    for (int t = 0; t < 16; ++t) wcd[t] = (double)enc_w2[(ch * 16 + t) * 64 + lane];
    #pragma unroll
    for (int t2 = 0; t2 < 8; ++t2) {
      #pragma unroll
      for (int n = 0; n < 8; ++n) {
        const double2 hv = *(const double2*)&W.big.d[n][ch * 16 + t2 * 2];
        acc2[n] = fma(hv.x, wcd[t2 * 2], acc2[n]);
        acc2[n] = fma(hv.y, wcd[t2 * 2 + 1], acc2[n]);
      }
    }
  }
  WFENCE();                                  // h1 reads drained (WAR)
  #pragma unroll
  for (int n = 0; n < 8; ++n) W.big.d[n][lane] = acc2[n] > 0.0 ? acc2[n] : 0.0;
  WFENCE();                                  // h2 visible

  // ---- latent projection (fp64, split-k over lane halves) ----
  {
    const int r24 = lane & 31, g = lane >> 5;
    double a = 0.0;
    if (r24 < 24) {
      const int n = r24 / 3, l = r24 - n * 3;
      a = g ? 0.0 : (double)s_b3e[l];
      const int k0 = g * 32;
      #pragma unroll 8
      for (int k = k0; k < k0 + 32; ++k) a = fma(W.big.d[n][k], (double)s_w3e[k * 3 + l], a);
    }
    const double b = __shfl_xor(a, 32);
    if (lane < 24) {
      const double tot = a + b;
      W.latSd[lane] = tot;
      W.latSf[lane] = (float)tot;
    }
  }
  WFENCE();                                  // latS visible

  // ---- normalize -> vis (fp64, lanes<24) ----
  if (lane < 24) {
    const int r = lane, l = r % 3;
    double s1 = 0.0;
    #pragma unroll
    for (int q = 0; q < 8; ++q) s1 += W.latSd[q * 3 + l];
    const double m = s1 * 0.125;
    double s2 = 0.0;
    #pragma unroll
    for (int q = 0; q < 8; ++q) s2 += (W.latSd[q * 3 + l] - m);
    const double m2 = s2 * 0.125;
    double s3 = 0.0;
    #pragma unroll
    for (int q = 0; q < 8; ++q) { double dv = W.latSd[q * 3 + l] - m - m2; s3 += dv * dv; }
    const double stdv = sqrt(s3 / 7.0) + 1e-8;
    const double visv = (W.latSd[r] - m) / stdv;
    W.visSd[r] = visv;
    if (active) out[(size_t)B * 48 + (size_t)s * 24 + r] = (float)visv;
  }
  WFENCE();                                  // visSd visible

  // ---- Gabriel graph (fp64, lane = (i,j)) ----
  const int gi = lane >> 3, gj = lane & 7;
  const double pi0 = W.visSd[gi * 3], pi1 = W.visSd[gi * 3 + 1], pi2 = W.visSd[gi * 3 + 2];
  const double pj0 = W.visSd[gj * 3], pj1 = W.visSd[gj * 3 + 1], pj2 = W.visSd[gj * 3 + 2];
  const double mid0 = (pi0 + pj0) * 0.5, mid1 = (pi1 + pj1) * 0.5, mid2 = (pi2 + pj2) * 0.5;
  const double dr0 = pi0 - mid0, dr1 = pi1 - mid1, dr2 = pi2 - mid2;
  const double r2 = dr0 * dr0 + dr1 * dr1 + dr2 * dr2;
  bool viol = false;
  #pragma unroll
  for (int k = 0; k < 8; ++k) {
    const double a0 = W.visSd[k * 3] - mid0;
    const double a1 = W.visSd[k * 3 + 1] - mid1;
    const double a2 = W.visSd[k * 3 + 2] - mid2;
    const double d2 = a0 * a0 + a1 * a1 + a2 * a2;
    viol = viol || ((k != gi) && (k != gj) && (d2 < r2));
  }
  const double dd0 = pi0 - pj0, dd1 = pi1 - pj1, dd2 = pi2 - pj2;
  const double distd = sqrt(dd0 * dd0 + dd1 * dd1 + dd2 * dd2 + 1e-30);
  const bool adjb  = (!viol) && (gi != gj);
  const bool maskb = adjb || (gi == gj);
  const float adjf = adjb ? 1.0f : 0.0f;
  if (active) out[(size_t)B * 72 + (size_t)s * 64 + lane] = adjf;
  const float distf = (float)distd;
  float ne = adjf, sd = adjb ? distf : 0.0f;
  #pragma unroll
  for (int d = 1; d < 64; d <<= 1) { ne += __shfl_xor(ne, d); sd += __shfl_xor(sd, d); }
  const float mean_attr = sd / fmaxf(ne, 1.0f);
  const float eat = (gi == gj) ? mean_attr : distf;

  // ---- GAT1 source/target transforms (fp32, lane = channel) ----
  float xlr[8], xrr[8];
  #pragma unroll
  for (int n = 0; n < 8; ++n) {
    const float a0 = W.latSf[n * 3], a1 = W.latSf[n * 3 + 1], a2 = W.latSf[n * 3 + 2];
    xlr[n] = fmaf(a2, wl2, fmaf(a1, wl1, fmaf(a0, wl0, blc)));
    xrr[n] = fmaf(a2, wr2, fmaf(a1, wr1, fmaf(a0, wr0, brc)));
    W.big.f[0][n][lane] = xlr[n];
    W.big.f[1][n][lane] = xrr[n];
  }
  WFENCE();                                  // xl/xr visible

  // ---- GAT1 attention logits (lane = (i,j)) ----
  float ev = 0.0f;
  #pragma unroll
  for (int c4 = 0; c4 < 16; ++c4) {
    const float4 xlv = *(const float4*)&W.big.f[0][gj][c4 * 4];
    const float4 xrv = *(const float4*)&W.big.f[1][gi][c4 * 4];
    const float4 wev = *(const float4*)&s_we1[c4 * 4];
    const float4 atv = *(const float4*)&s_att1[c4 * 4];
    float h;
    h = fmaf(eat, wev.x, xrv.x + xlv.x); ev = fmaf(fmaxf(h, 0.f) + 0.2f * fminf(h, 0.f), atv.x, ev);
    h = fmaf(eat, wev.y, xrv.y + xlv.y); ev = fmaf(fmaxf(h, 0.f) + 0.2f * fminf(h, 0.f), atv.y, ev);
    h = fmaf(eat, wev.z, xrv.z + xlv.z); ev = fmaf(fmaxf(h, 0.f) + 0.2f * fminf(h, 0.f), atv.z, ev);
    h = fmaf(eat, wev.w, xrv.w + xlv.w); ev = fmaf(fmaxf(h, 0.f) + 0.2f * fminf(h, 0.f), atv.w, ev);
  }
  {
    float em = maskb ? ev : -1e30f;
    float mx = em;
    mx = fmaxf(mx, __shfl_xor(mx, 1)); mx = fmaxf(mx, __shfl_xor(mx, 2)); mx = fmaxf(mx, __shfl_xor(mx, 4));
    float p = __expf(em - mx);
    float ssum = p;
    ssum += __shfl_xor(ssum, 1); ssum += __shfl_xor(ssum, 2); ssum += __shfl_xor(ssum, 4);
    W.alphaS[lane] = (p / ssum) * (maskb ? 1.0f : 0.0f);
  }
  WFENCE();                                  // alpha visible + f[] reads drained

  // ---- GAT1 aggregation + relu (lane = channel) ----
  float hg[8];
  #pragma unroll
  for (int i = 0; i < 8; ++i) {
    const float4 q0 = *(const float4*)&W.alphaS[i * 8];
    const float4 q1 = *(const float4*)&W.alphaS[i * 8 + 4];
    float a = g1bias_c;
    a = fmaf(q0.x, xlr[0], a); a = fmaf(q0.y, xlr[1], a);
    a = fmaf(q0.z, xlr[2], a); a = fmaf(q0.w, xlr[3], a);
    a = fmaf(q1.x, xlr[4], a); a = fmaf(q1.y, xlr[5], a);
    a = fmaf(q1.z, xlr[6], a); a = fmaf(q1.w, xlr[7], a);
    hg[i] = fmaxf(a, 0.0f);
  }
  WFENCE();                                  // alphaS reads drained (WAR on f[0])
  #pragma unroll
  for (int i = 0; i < 8; ++i) W.big.f[0][i][lane] = hg[i];
  WFENCE();                                  // h1 (GAT1 out) visible

  // ---- GAT2 transforms (lanes<48: 24 for xl2, 24 for xr2) ----
  if (lane < 48) {
    const int g = lane / 24, r = lane - g * 24, n = r / 3, l = r - n * 3;
    const float* wsel = g ? s_g2wr : s_g2wl;
    float a = g ? s_g2br[l] : s_g2bl[l];
    #pragma unroll 8
    for (int k = 0; k < 64; ++k) a = fmaf(W.big.f[0][n][k], wsel[k * 3 + l], a);
    if (g) W.xr2S[r] = a; else W.xl2S[r] = a;
  }
  WFENCE();                                  // xl2/xr2 visible

  // ---- GAT2 attention (lane = (i,j)) ----
  float e2 = 0.0f;
  #pragma unroll
  for (int l = 0; l < 3; ++l) {
    const float hh = fmaf(eat, s_g2we[l], W.xr2S[gi * 3 + l] + W.xl2S[gj * 3 + l]);
    e2 = fmaf(fmaxf(hh, 0.f) + 0.2f * fminf(hh, 0.f), s_g2att[l], e2);
  }
  {
    float em = maskb ? e2 : -1e30f;
    float mx = em;
    mx = fmaxf(mx, __shfl_xor(mx, 1)); mx = fmaxf(mx, __shfl_xor(mx, 2)); mx = fmaxf(mx, __shfl_xor(mx, 4));
    float p = __expf(em - mx);
    float ssum = p;
    ssum += __shfl_xor(ssum, 1); ssum += __shfl_xor(ssum, 2); ssum += __shfl_xor(ssum, 4);
    W.alphaS[lane] = (p / ssum) * (maskb ? 1.0f : 0.0f);
  }
  WFENCE();                                  // alpha2 visible

  // ---- GAT2 aggregation + skip connection (lanes<24) ----
  if (lane < 24) {
    const int r = lane, n = r / 3, l = r - n * 3;
    float a = s_g2bias[l];
    #pragma unroll
    for (int j = 0; j < 8; ++j) a = fmaf(W.alphaS[n * 8 + j], W.xl2S[j * 3 + l], a);
    const float cb = a + W.latSf[n * 3] * s_skw[l] + W.latSf[n * 3 + 1] * s_skw[3 + l]
                       + W.latSf[n * 3 + 2] * s_skw[6 + l] + s_skb[l];
    W.combS[r] = cb;
  }
  WFENCE();                                  // combS visible

  // ---- decoder layer 1 (lane = channel) ----
  #pragma unroll
  for (int n = 0; n < 8; ++n) {
    const float c0 = W.combS[n * 3], c1 = W.combS[n * 3 + 1], c2 = W.combS[n * 3 + 2];
    const float d1 = fmaf(c2, dwc2, fmaf(c1, dwc1, fmaf(c0, dwc0, db1c)));
    W.big.f[0][n][lane] = fmaxf(d1, 0.0f);
  }
  WFENCE();                                  // dec-h1 visible

  // ---- decoder layer 2 (fp32 64x64) ----
  float accf[8];
  #pragma unroll
  for (int n = 0; n < 8; ++n) accf[n] = db2c;
  #pragma unroll
  for (int ch = 0; ch < 2; ++ch) {
    float wc[32];
    #pragma unroll
    for (int t = 0; t < 32; ++t) wc[t] = dec_w2[(ch * 32 + t) * 64 + lane];
    #pragma unroll
    for (int t4 = 0; t4 < 8; ++t4) {
      #pragma unroll
      for (int n = 0; n < 8; ++n) {
        const float4 hv = *(const float4*)&W.big.f[0][n][ch * 32 + t4 * 4];
        accf[n] = fmaf(hv.x, wc[t4 * 4], accf[n]);
        accf[n] = fmaf(hv.y, wc[t4 * 4 + 1], accf[n]);
        accf[n] = fmaf(hv.z, wc[t4 * 4 + 2], accf[n]);
        accf[n] = fmaf(hv.w, wc[t4 * 4 + 3], accf[n]);
      }
    }
  }
  WFENCE();                                  // f[0] reads drained (WAR on f[1])
  #pragma unroll
  for (int n = 0; n < 8; ++n) W.big.f[1][n][lane] = fmaxf(accf[n], 0.0f);
  WFENCE();                                  // dec-h2 visible

  // ---- decoder output projection -> rec (fp32, split-k over lane halves) ----
  {
    const int r24 = lane & 31, g = lane >> 5;
    float a = 0.0f;
    if (r24 < 24) {
      const int n = r24 / 3, l = r24 - n * 3;
      a = g ? 0.0f : s_b3d[l];
      const int k0 = g * 32;
      #pragma unroll 8
      for (int k = k0; k < k0 + 32; ++k) a = fmaf(W.big.f[1][n][k], s_w3d[k * 3 + l], a);
    }
    const float b = __shfl_xor(a, 32);
    if (active && lane < 24) {
      out[(size_t)B * 24 + (size_t)s * 24 + lane] = a + b;
    }
  }
}

extern "C" void kernel_launch(void* const* d_in, const int* in_sizes, int n_in,
                              void* d_out, int out_size, void* d_ws, size_t ws_size,
                              hipStream_t stream) {
  const int B = in_sizes[0] / 8;
  const float* x       = (const float*)d_in[0];
  const float* enc_w1  = (const float*)d_in[1];
  const float* enc_b1  = (const float*)d_in[2];
  const float* enc_w2  = (const float*)d_in[3];
  const float* enc_b2  = (const float*)d_in[4];
  const float* enc_w3  = (const float*)d_in[5];
  const float* enc_b3  = (const float*)d_in[6];
  const float* g1_wl   = (const float*)d_in[7];
  const float* g1_bl   = (const float*)d_in[8];
  const float* g1_wr   = (const float*)d_in[9];
  const float* g1_br   = (const float*)d_in[10];
  const float* g1_we   = (const float*)d_in[11];
  const float* g1_att  = (const float*)d_in[12];
  const float* g1_bias = (const float*)d_in[13];
  const float* g2_wl   = (const float*)d_in[14];
  const float* g2_bl   = (const float*)d_in[15];
  const float* g2_wr   = (const float*)d_in[16];
  const float* g2_br   = (const float*)d_in[17];
  const float* g2_we   = (const float*)d_in[18];
  const float* g2_att  = (const float*)d_in[19];
  const float* g2_bias = (const float*)d_in[20];
  const float* skip_w  = (const float*)d_in[21];
  const float* skip_b  = (const float*)d_in[22];
  const float* dec_w1  = (const float*)d_in[23];
  const float* dec_b1  = (const float*)d_in[24];
  const float* dec_w2  = (const float*)d_in[25];
  const float* dec_b2  = (const float*)d_in[26];
  const float* dec_w3  = (const float*)d_in[27];
  const float* dec_b3  = (const float*)d_in[28];
  float* out = (float*)d_out;

  const int nblk = (B + 3) / 4;
  gae_fused<<<nblk, 256, 0, stream>>>(x,
      enc_w1, enc_b1, enc_w2, enc_b2, enc_w3, enc_b3,
      g1_wl, g1_bl, g1_wr, g1_br, g1_we, g1_att, g1_bias,
      g2_wl, g2_bl, g2_wr, g2_br, g2_we, g2_att, g2_bias,
      skip_w, skip_b, dec_w1, dec_b1, dec_w2, dec_b2, dec_w3, dec_b3,
      out, B);
}